// Round 9
// baseline (171.451 us; speedup 1.0000x reference)
//
#include <hip/hip_runtime.h>

#define NCAM 4
#define C 336
#define H 96
#define W 176
#define D 6
#define HB 240
#define WB 120
#define HW (H * W)        // 16896
#define CSTRIDE 352       // padded column stride (bf16 elems) = 704 B = 11 lines

typedef unsigned u32x4 __attribute__((ext_vector_type(4)));

static __device__ __forceinline__ unsigned short f2bf(float f) {
    unsigned u = __float_as_uint(f);
    unsigned r = (u + 0x7fffu + ((u >> 16) & 1u)) >> 16;   // RNE
    return (unsigned short)r;
}

// ---------------------------------------------------------------------------
// Pass 1: feat[cam][c][h*w] (f32) -> tfeat[cam][h*w][CSTRIDE] (bf16, padded
// so every channel column starts 64B-aligned and spans exactly 11 lines).
// ---------------------------------------------------------------------------
__global__ __launch_bounds__(256)
void vp_transpose_bf16(const float* __restrict__ in,
                       unsigned short* __restrict__ out) {
    __shared__ float tile[64][33];
    const int cam = blockIdx.z;
    const int hw0 = blockIdx.x * 64;
    const int c0  = blockIdx.y * 32;
    const int tid = threadIdx.x;

    const int hwq = tid & 15;
    const int cl  = tid >> 4;
    const float* src = in + (size_t)cam * C * HW + hw0 + hwq * 4;
#pragma unroll
    for (int cc = 0; cc < 2; ++cc) {
        const int c = c0 + cl + cc * 16;
        if (c < C) {
            const float4 v = *(const float4*)(src + (size_t)c * HW);
            tile[hwq * 4 + 0][cl + cc * 16] = v.x;
            tile[hwq * 4 + 1][cl + cc * 16] = v.y;
            tile[hwq * 4 + 2][cl + cc * 16] = v.z;
            tile[hwq * 4 + 3][cl + cc * 16] = v.w;
        }
    }
    __syncthreads();

    const int hw  = tid >> 2;
    const int oct = tid & 3;
    const int cs  = c0 + oct * 8;
    if (cs < C) {
        uint4 r;
        unsigned* pr = (unsigned*)&r;
#pragma unroll
        for (int k = 0; k < 4; ++k) {
            unsigned lo = f2bf(tile[hw][oct * 8 + 2 * k]);
            unsigned hi = f2bf(tile[hw][oct * 8 + 2 * k + 1]);
            pr[k] = lo | (hi << 16);
        }
        *(uint4*)(out + (size_t)cam * HW * CSTRIDE +
                  (size_t)(hw0 + hw) * CSTRIDE + cs) = r;
    }
}

// ---------------------------------------------------------------------------
// Pass 2: EXACT R7 structure (proven passing, 139 us): one 512-thread block
// per (d, hb); 8 waves x 15 wb; 3 cparts of 112 c; 16 asm global_load_dwordx4
// per cpart per wave with counted vmcnt (never drained to 0 across stores);
// two-half LDS dump + float2 sweep. Only change: padded CSTRIDE offsets.
// ---------------------------------------------------------------------------
#define LOADQ(dst, off, TF) \
    asm volatile("global_load_dwordx4 %0, %1, %2" \
                 : "=v"(dst) : "v"(off), "s"(TF))

#define VMWAIT(N) \
    do { asm volatile("s_waitcnt vmcnt(" #N ")" ::: "memory"); \
         __builtin_amdgcn_sched_barrier(0); } while (0)

#define LBAR() \
    do { asm volatile("s_waitcnt lgkmcnt(0)" ::: "memory"); \
         __builtin_amdgcn_sched_barrier(0); \
         __builtin_amdgcn_s_barrier(); } while (0)

#define ISSUE16() \
    do { \
        _Pragma("unroll") \
        for (int cam = 0; cam < 4; ++cam) { \
            _Pragma("unroll") \
            for (int wbi = 0; wbi < 4; ++wbi) { \
                LOADQ(q[cam][wbi], voff[cam][wbi], tfeat); \
                voff[cam][wbi] += 224u; \
            } \
        } \
    } while (0)

#define FMACAM(cam, NW, OP) \
    do { \
        VMWAIT(NW); \
        _Pragma("unroll") \
        for (int wbi = 0; wbi < 4; ++wbi) { \
            const float w = s_wgt[cam][wbc[wbi]]; \
            const u32x4 v = q[cam][wbi]; \
            acc[wbi][0] OP w * __uint_as_float(v[0] << 16); \
            acc[wbi][1] OP w * __uint_as_float(v[0] & 0xffff0000u); \
            acc[wbi][2] OP w * __uint_as_float(v[1] << 16); \
            acc[wbi][3] OP w * __uint_as_float(v[1] & 0xffff0000u); \
            acc[wbi][4] OP w * __uint_as_float(v[2] << 16); \
            acc[wbi][5] OP w * __uint_as_float(v[2] & 0xffff0000u); \
            acc[wbi][6] OP w * __uint_as_float(v[3] << 16); \
            acc[wbi][7] OP w * __uint_as_float(v[3] & 0xffff0000u); \
        } \
    } while (0)

__global__ __launch_bounds__(512, 4)
void vp_gather_bf16(const unsigned short* __restrict__ tfeat,
                    const int* __restrict__ pu, const int* __restrict__ pv,
                    const int* __restrict__ pvalid,
                    const float* __restrict__ pdens,
                    float* __restrict__ out) {
    __shared__ int   s_off[NCAM][WB];
    __shared__ float s_wgt[NCAM][WB];
    __shared__ float s_acc[56][121];

    const int d   = blockIdx.x / HB;
    const int hb  = blockIdx.x % HB;
    const int tid = threadIdx.x;

    if (tid < NCAM * WB) {
        const int cam = tid / WB, wb = tid % WB;
        const size_t pidx = ((size_t)(cam * D + d) * HB + hb) * WB + wb;
        s_wgt[cam][wb] = pvalid[pidx] ? pdens[pidx] : 0.0f;
        s_off[cam][wb] = cam * (HW * CSTRIDE) + (pv[pidx] * W + pu[pidx]) * CSTRIDE;
    }
    __syncthreads();

    const int wave  = tid >> 6;                // 0..7, owns wb [wave*15, +15)
    const int lane  = tid & 63;
    const int cq    = lane & 15;               // active < 14
    const int wbsub = lane >> 4;               // 0..3
    const bool cact = (cq < 14);
    const int coff  = (cact ? cq : 13) * 8;    // c-octet element offset

    int wbc[4];
#pragma unroll
    for (int wbi = 0; wbi < 4; ++wbi) {
        const int wbl = wbsub + 4 * wbi;       // active < 15
        wbc[wbi] = wave * 15 + (wbl < 15 ? wbl : 14);
    }

    unsigned voff[4][4];                        // byte offsets into tfeat
#pragma unroll
    for (int cam = 0; cam < 4; ++cam)
#pragma unroll
        for (int wbi = 0; wbi < 4; ++wbi)
            voff[cam][wbi] = (unsigned)(s_off[cam][wbc[wbi]] + coff) * 2u;

    u32x4 q[4][4];
    float acc[4][8];

    // dump acc -> LDS and sweep-store, two halves of 56 c-rows each.
    auto dumpstore = [&](int cp) {
#pragma unroll
        for (int half = 0; half < 2; ++half) {
            if (cact && cq >= half * 7 && cq < half * 7 + 7) {
                const int rbase = (cq - half * 7) * 8;
#pragma unroll
                for (int wbi = 0; wbi < 4; ++wbi) {
                    const int wbl = wbsub + 4 * wbi;
                    if (wbl < 15) {
#pragma unroll
                        for (int j = 0; j < 8; ++j)
                            s_acc[rbase + j][wave * 15 + wbl] = acc[wbi][j];
                    }
                }
            }
            LBAR();
            const int wp = tid & 63;           // active < 60
            const int rb = tid >> 6;           // 0..7
            if (wp < 60) {
#pragma unroll
                for (int k = 0; k < 7; ++k) {
                    const int r = rb + 8 * k;
                    const int c = cp * 112 + half * 56 + r;
                    float2 v;
                    v.x = s_acc[r][wp * 2 + 0];
                    v.y = s_acc[r][wp * 2 + 1];
                    *(float2*)(out + (((size_t)d * C + c) * HB + hb) * WB +
                               wp * 2) = v;
                }
            }
            LBAR();
        }
    };

    ISSUE16();                                  // cp0 loads in flight
    // ---- cp0: no prior stores outstanding -> waits 12/8/4/0
    FMACAM(0, 12, =);
    FMACAM(1, 8, +=);
    FMACAM(2, 4, +=);
    FMACAM(3, 0, +=);
    ISSUE16();                                  // cp1 loads (before stores)
    dumpstore(0);                               // 14 stores join the queue
    // ---- cp1: 16 loads oldest, 14 stores newer -> waits 26/22/18/14
    FMACAM(0, 26, =);
    FMACAM(1, 22, +=);
    FMACAM(2, 18, +=);
    FMACAM(3, 14, +=);
    ISSUE16();                                  // cp2 loads
    dumpstore(1);
    // ---- cp2
    FMACAM(0, 26, =);
    FMACAM(1, 22, +=);
    FMACAM(2, 18, +=);
    FMACAM(3, 14, +=);
    dumpstore(2);
}

extern "C" void kernel_launch(void* const* d_in, const int* in_sizes, int n_in,
                              void* d_out, int out_size, void* d_ws,
                              size_t ws_size, hipStream_t stream) {
    const float* feat  = (const float*)d_in[0];
    const int* pu      = (const int*)d_in[1];
    const int* pv      = (const int*)d_in[2];
    const int* pvalid  = (const int*)d_in[3];
    const float* pdens = (const float*)d_in[4];
    float* out         = (float*)d_out;

    unsigned short* tfeat = (unsigned short*)d_ws;   // 47.6 MB padded

    dim3 tgrid(HW / 64, (C + 31) / 32, NCAM);
    vp_transpose_bf16<<<tgrid, 256, 0, stream>>>(feat, tfeat);

    vp_gather_bf16<<<D * HB, 512, 0, stream>>>(tfeat, pu, pv, pvalid, pdens,
                                               out);
}

// Round 11
// 170.451 us; speedup vs baseline: 1.0059x; 1.0059x over previous
//
#include <hip/hip_runtime.h>

#define NCAM 4
#define C 336
#define H 96
#define W 176
#define D 6
#define HB 240
#define WB 120
#define HW (H * W)        // 16896
#define CSTRIDE 352       // padded column stride (bf16 elems) = 704 B = 11 lines

typedef unsigned u32x4 __attribute__((ext_vector_type(4)));

static __device__ __forceinline__ unsigned short f2bf(float f) {
    unsigned u = __float_as_uint(f);
    unsigned r = (u + 0x7fffu + ((u >> 16) & 1u)) >> 16;   // RNE
    return (unsigned short)r;
}

// ---------------------------------------------------------------------------
// Pass 1: feat[cam][c][h*w] (f32) -> tfeat[cam][h*w][CSTRIDE] (bf16, padded
// so every channel column starts 64B-aligned and spans exactly 11 lines).
// ---------------------------------------------------------------------------
__global__ __launch_bounds__(256)
void vp_transpose_bf16(const float* __restrict__ in,
                       unsigned short* __restrict__ out) {
    __shared__ float tile[64][33];
    const int cam = blockIdx.z;
    const int hw0 = blockIdx.x * 64;
    const int c0  = blockIdx.y * 32;
    const int tid = threadIdx.x;

    const int hwq = tid & 15;
    const int cl  = tid >> 4;
    const float* src = in + (size_t)cam * C * HW + hw0 + hwq * 4;
#pragma unroll
    for (int cc = 0; cc < 2; ++cc) {
        const int c = c0 + cl + cc * 16;
        if (c < C) {
            const float4 v = *(const float4*)(src + (size_t)c * HW);
            tile[hwq * 4 + 0][cl + cc * 16] = v.x;
            tile[hwq * 4 + 1][cl + cc * 16] = v.y;
            tile[hwq * 4 + 2][cl + cc * 16] = v.z;
            tile[hwq * 4 + 3][cl + cc * 16] = v.w;
        }
    }
    __syncthreads();

    const int hw  = tid >> 2;
    const int oct = tid & 3;
    const int cs  = c0 + oct * 8;
    if (cs < C) {
        uint4 r;
        unsigned* pr = (unsigned*)&r;
#pragma unroll
        for (int k = 0; k < 4; ++k) {
            unsigned lo = f2bf(tile[hw][oct * 8 + 2 * k]);
            unsigned hi = f2bf(tile[hw][oct * 8 + 2 * k + 1]);
            pr[k] = lo | (hi << 16);
        }
        *(uint4*)(out + (size_t)cam * HW * CSTRIDE +
                  (size_t)(hw0 + hw) * CSTRIDE + cs) = r;
    }
}

// ---------------------------------------------------------------------------
// Pass 2: EXACT R9 kernel (proven passing, 137.6 us gather). One 512-thread
// block per (d, hb); 8 waves x 15 wb; 3 cparts of 112 c; 16 asm
// global_load_dwordx4 per cpart per wave with counted vmcnt (never drained
// to 0 across stores); two-half LDS dump + float2 sweep.
// DO NOT perturb codegen here: launch_bounds changes (R10) and sweep
// restructuring (R8) both inserted scratch/copies into the vmcnt stream and
// produced NaN. The hand-counted waits are only valid for this exact form.
// ---------------------------------------------------------------------------
#define LOADQ(dst, off, TF) \
    asm volatile("global_load_dwordx4 %0, %1, %2" \
                 : "=v"(dst) : "v"(off), "s"(TF))

#define VMWAIT(N) \
    do { asm volatile("s_waitcnt vmcnt(" #N ")" ::: "memory"); \
         __builtin_amdgcn_sched_barrier(0); } while (0)

#define LBAR() \
    do { asm volatile("s_waitcnt lgkmcnt(0)" ::: "memory"); \
         __builtin_amdgcn_sched_barrier(0); \
         __builtin_amdgcn_s_barrier(); } while (0)

#define ISSUE16() \
    do { \
        _Pragma("unroll") \
        for (int cam = 0; cam < 4; ++cam) { \
            _Pragma("unroll") \
            for (int wbi = 0; wbi < 4; ++wbi) { \
                LOADQ(q[cam][wbi], voff[cam][wbi], tfeat); \
                voff[cam][wbi] += 224u; \
            } \
        } \
    } while (0)

#define FMACAM(cam, NW, OP) \
    do { \
        VMWAIT(NW); \
        _Pragma("unroll") \
        for (int wbi = 0; wbi < 4; ++wbi) { \
            const float w = s_wgt[cam][wbc[wbi]]; \
            const u32x4 v = q[cam][wbi]; \
            acc[wbi][0] OP w * __uint_as_float(v[0] << 16); \
            acc[wbi][1] OP w * __uint_as_float(v[0] & 0xffff0000u); \
            acc[wbi][2] OP w * __uint_as_float(v[1] << 16); \
            acc[wbi][3] OP w * __uint_as_float(v[1] & 0xffff0000u); \
            acc[wbi][4] OP w * __uint_as_float(v[2] << 16); \
            acc[wbi][5] OP w * __uint_as_float(v[2] & 0xffff0000u); \
            acc[wbi][6] OP w * __uint_as_float(v[3] << 16); \
            acc[wbi][7] OP w * __uint_as_float(v[3] & 0xffff0000u); \
        } \
    } while (0)

__global__ __launch_bounds__(512, 4)
void vp_gather_bf16(const unsigned short* __restrict__ tfeat,
                    const int* __restrict__ pu, const int* __restrict__ pv,
                    const int* __restrict__ pvalid,
                    const float* __restrict__ pdens,
                    float* __restrict__ out) {
    __shared__ int   s_off[NCAM][WB];
    __shared__ float s_wgt[NCAM][WB];
    __shared__ float s_acc[56][121];

    const int d   = blockIdx.x / HB;
    const int hb  = blockIdx.x % HB;
    const int tid = threadIdx.x;

    if (tid < NCAM * WB) {
        const int cam = tid / WB, wb = tid % WB;
        const size_t pidx = ((size_t)(cam * D + d) * HB + hb) * WB + wb;
        s_wgt[cam][wb] = pvalid[pidx] ? pdens[pidx] : 0.0f;
        s_off[cam][wb] = cam * (HW * CSTRIDE) + (pv[pidx] * W + pu[pidx]) * CSTRIDE;
    }
    __syncthreads();

    const int wave  = tid >> 6;                // 0..7, owns wb [wave*15, +15)
    const int lane  = tid & 63;
    const int cq    = lane & 15;               // active < 14
    const int wbsub = lane >> 4;               // 0..3
    const bool cact = (cq < 14);
    const int coff  = (cact ? cq : 13) * 8;    // c-octet element offset

    int wbc[4];
#pragma unroll
    for (int wbi = 0; wbi < 4; ++wbi) {
        const int wbl = wbsub + 4 * wbi;       // active < 15
        wbc[wbi] = wave * 15 + (wbl < 15 ? wbl : 14);
    }

    unsigned voff[4][4];                        // byte offsets into tfeat
#pragma unroll
    for (int cam = 0; cam < 4; ++cam)
#pragma unroll
        for (int wbi = 0; wbi < 4; ++wbi)
            voff[cam][wbi] = (unsigned)(s_off[cam][wbc[wbi]] + coff) * 2u;

    u32x4 q[4][4];
    float acc[4][8];

    // dump acc -> LDS and sweep-store, two halves of 56 c-rows each.
    auto dumpstore = [&](int cp) {
#pragma unroll
        for (int half = 0; half < 2; ++half) {
            if (cact && cq >= half * 7 && cq < half * 7 + 7) {
                const int rbase = (cq - half * 7) * 8;
#pragma unroll
                for (int wbi = 0; wbi < 4; ++wbi) {
                    const int wbl = wbsub + 4 * wbi;
                    if (wbl < 15) {
#pragma unroll
                        for (int j = 0; j < 8; ++j)
                            s_acc[rbase + j][wave * 15 + wbl] = acc[wbi][j];
                    }
                }
            }
            LBAR();
            const int wp = tid & 63;           // active < 60
            const int rb = tid >> 6;           // 0..7
            if (wp < 60) {
#pragma unroll
                for (int k = 0; k < 7; ++k) {
                    const int r = rb + 8 * k;
                    const int c = cp * 112 + half * 56 + r;
                    float2 v;
                    v.x = s_acc[r][wp * 2 + 0];
                    v.y = s_acc[r][wp * 2 + 1];
                    *(float2*)(out + (((size_t)d * C + c) * HB + hb) * WB +
                               wp * 2) = v;
                }
            }
            LBAR();
        }
    };

    ISSUE16();                                  // cp0 loads in flight
    // ---- cp0: no prior stores outstanding -> waits 12/8/4/0
    FMACAM(0, 12, =);
    FMACAM(1, 8, +=);
    FMACAM(2, 4, +=);
    FMACAM(3, 0, +=);
    ISSUE16();                                  // cp1 loads (before stores)
    dumpstore(0);                               // 14 stores join the queue
    // ---- cp1: 16 loads oldest, 14 stores newer -> waits 26/22/18/14
    FMACAM(0, 26, =);
    FMACAM(1, 22, +=);
    FMACAM(2, 18, +=);
    FMACAM(3, 14, +=);
    ISSUE16();                                  // cp2 loads
    dumpstore(1);
    // ---- cp2
    FMACAM(0, 26, =);
    FMACAM(1, 22, +=);
    FMACAM(2, 18, +=);
    FMACAM(3, 14, +=);
    dumpstore(2);
}

extern "C" void kernel_launch(void* const* d_in, const int* in_sizes, int n_in,
                              void* d_out, int out_size, void* d_ws,
                              size_t ws_size, hipStream_t stream) {
    const float* feat  = (const float*)d_in[0];
    const int* pu      = (const int*)d_in[1];
    const int* pv      = (const int*)d_in[2];
    const int* pvalid  = (const int*)d_in[3];
    const float* pdens = (const float*)d_in[4];
    float* out         = (float*)d_out;

    unsigned short* tfeat = (unsigned short*)d_ws;   // 47.6 MB padded

    dim3 tgrid(HW / 64, (C + 31) / 32, NCAM);
    vp_transpose_bf16<<<tgrid, 256, 0, stream>>>(feat, tfeat);

    vp_gather_bf16<<<D * HB, 512, 0, stream>>>(tfeat, pu, pv, pvalid, pdens,
                                               out);
}